// Round 4
// baseline (853.140 us; speedup 1.0000x reference)
//
#include <hip/hip_runtime.h>
#include <math.h>

// LSD (local shape descriptors), 128^3, 8 labels, sigma=5, truncate=3 -> 31-tap kernel.
//
// Algebra: for label mask m, define G_{abc} = (k_a *_z)(k_b *_y)(k_c *_x) m with
//   k0(u)=w(u), k1(u)=u w(u), k2(u)=u^2 w(u)  (w = normalized gaussian).
// At a voxel with mass=G000>0, p=G100/mass, q=G010/mass, s=G001/mass:
//   mean_offset = 0.5 - {p,q,s}/(2 sigma);  cov_ab = (G../mass - ..)/sigma^2.
// Translation-invariant: coords input not needed. Masks disjoint -> each voxel
// takes only its own label's descriptor.
//
// R1: XCD z-slab swizzle (7.25x pass_y overfetch fixed).
// R3: register-tiled sliding-window convs (VMEM-issue bound fixed), 794 us.
// R4: fuse y-conv + x-conv + epilogue into one kernel. x-conv only needs the
//     6 B-channels of its OWN row -> y-conv slides in registers, parks rows in
//     LDS (16 rows x 6 ch x 128 = 48 KB), barrier, x-conv reads LDS. Kills the
//     B round-trip (measured 50 MB HBM WRITE per pass_y dispatch + pass_x
//     window re-reads, ~770 MB total) and 8 dispatch tails.

constexpr int NV = 128 * 128 * 128;
constexpr int SLICE = 128 * 128;
constexpr int R = 15;
constexpr int KL = 31;

struct Kw { float k0[KL]; float k1[KL]; float k2[KL]; };

__device__ __forceinline__ void fma4(float4& a, float w, const float4& b) {
    a.x = fmaf(w, b.x, a.x); a.y = fmaf(w, b.y, a.y);
    a.z = fmaf(w, b.z, a.z); a.w = fmaf(w, b.w, a.w);
}

__device__ __forceinline__ float4 load_mask4(const unsigned char* p, int lab) {
    unsigned int u = *(const unsigned int*)p;
    return make_float4(((u       ) & 255u) == (unsigned)lab ? 1.f : 0.f,
                       ((u >>  8 ) & 255u) == (unsigned)lab ? 1.f : 0.f,
                       ((u >> 16 ) & 255u) == (unsigned)lab ? 1.f : 0.f,
                       ((u >> 24 ) & 255u) == (unsigned)lab ? 1.f : 0.f);
}
__device__ __forceinline__ float4 load_mask4(const int* p, int lab) {
    int4 s = *(const int4*)p;
    return make_float4(s.x == lab ? 1.f : 0.f, s.y == lab ? 1.f : 0.f,
                       s.z == lab ? 1.f : 0.f, s.w == lab ? 1.f : 0.f);
}

// ---------------- pass_z: seg -> A[3] (z-conv), tile: 4x (vec) x 4z --------
template <typename ST>
__global__ __launch_bounds__(256) void pass_z_t(const ST* __restrict__ seg,
                                                float* __restrict__ A,
                                                int label, Kw kw) {
    __shared__ float kp[3][37];           // zero-padded: kp[c][i] = k_c[i-3]
    if (threadIdx.x == 0) {
#pragma unroll
        for (int i = 0; i < 37; ++i) {
            int j = i - 3; bool ok = (j >= 0) && (j < KL);
            kp[0][i] = ok ? kw.k0[j] : 0.f;
            kp[1][i] = ok ? kw.k1[j] : 0.f;
            kp[2][i] = ok ? kw.k2[j] : 0.f;
        }
    }
    __syncthreads();
    const int h = blockIdx.x, g = h & 7, l = h >> 3;       // 512 blocks
    const int tx = threadIdx.x & 31, ty = threadIdx.x >> 5;
    const int x0 = tx * 4;
    const int z0 = 16 * g + 4 * (l & 3);                   // XCD g owns z [16g,16g+16)
    const int y  = (l >> 2) * 8 + ty;

    float4 acc[4][3];
#pragma unroll
    for (int t = 0; t < 4; ++t)
#pragma unroll
        for (int c = 0; c < 3; ++c) acc[t][c] = make_float4(0.f, 0.f, 0.f, 0.f);

    for (int j = 0; j < 34; ++j) {                         // window: 4 outs + 30
        int zz = z0 + j - R;                               // uniform per wave
        float4 m = make_float4(0.f, 0.f, 0.f, 0.f);
        if ((unsigned)zz < 128u)
            m = load_mask4(seg + (zz * SLICE + y * 128 + x0), label);
#pragma unroll
        for (int t = 0; t < 4; ++t) {
            int i = j - t + 3;                             // padded weight index
            fma4(acc[t][0], kp[0][i], m);
            fma4(acc[t][1], kp[1][i], m);
            fma4(acc[t][2], kp[2][i], m);
        }
    }
#pragma unroll
    for (int t = 0; t < 4; ++t) {
        int base = (z0 + t) * SLICE + y * 128 + x0;
#pragma unroll
        for (int c = 0; c < 3; ++c)
            *(float4*)(A + (size_t)c * NV + base) = acc[t][c];
    }
}

// ---- x-conv helper: window from an LDS row, exact tap bounds folded -------
template <int NO>
__device__ __forceinline__ void convx_lds(const float* __restrict__ Brow, int x0,
                                          const Kw& kw, float o0[4], float o1[4],
                                          float o2[4]) {
    float W[36];
#pragma unroll
    for (int i = 0; i < 9; ++i) {
        int off = x0 - 16 + 4 * i;
        float4 w = ((unsigned)off < 128u) ? *(const float4*)(Brow + off)
                                          : make_float4(0.f, 0.f, 0.f, 0.f);
        W[4 * i] = w.x; W[4 * i + 1] = w.y; W[4 * i + 2] = w.z; W[4 * i + 3] = w.w;
    }
#pragma unroll
    for (int t = 0; t < 4; ++t) {
#pragma unroll
        for (int j = 0; j < KL; ++j) {                     // u = t+j+1 in [1,34]
            float wv = W[t + j + 1];
            o0[t] = fmaf(kw.k0[j], wv, o0[t]);
            if (NO > 1) o1[t] = fmaf(kw.k1[j], wv, o1[t]);
            if (NO > 2) o2[t] = fmaf(kw.k2[j], wv, o2[t]);
        }
    }
}

// ---------------- pass_yx: A[3] -> out (y-conv -> LDS -> x-conv + epilogue)
// block = 128 thr: phase 1: (tx 0..31, tz 0..3) slides 4 y-outputs in regs;
// LDS holds 16 rows (4z x 4y) x 6 ch x 128. phase 2: 16 voxels/thread x-conv.
template <typename ST>
__global__ __launch_bounds__(128) void pass_yx(const float* __restrict__ A,
                                               const ST* __restrict__ seg,
                                               float* __restrict__ out,
                                               int label, Kw kw) {
    __shared__ float kp[3][37];
    __shared__ float Bs[16][6][128];                       // 48 KB
    if (threadIdx.x == 0) {
#pragma unroll
        for (int i = 0; i < 37; ++i) {
            int j = i - 3; bool ok = (j >= 0) && (j < KL);
            kp[0][i] = ok ? kw.k0[j] : 0.f;
            kp[1][i] = ok ? kw.k1[j] : 0.f;
            kp[2][i] = ok ? kw.k2[j] : 0.f;
        }
    }
    __syncthreads();

    const int h = blockIdx.x, g = h & 7, l = h >> 3;       // 1024 blocks
    const int tx = threadIdx.x & 31, tz = threadIdx.x >> 5; // tz 0..3
    const int x0 = tx * 4;
    const int zbase = 16 * g + 4 * (l & 3);                // XCD g owns z slab
    const int y0 = (l >> 2) * 4;                           // 32 y-tiles
    const int z = zbase + tz;
    const int zs = z * SLICE;

    // ---- phase 1: y-conv, 4 outputs sliding in registers ----
    float4 acc[6][4];                                      // [ch][t]
#pragma unroll
    for (int c = 0; c < 6; ++c)
#pragma unroll
        for (int t = 0; t < 4; ++t) acc[c][t] = make_float4(0.f, 0.f, 0.f, 0.f);

    for (int j = 0; j < 34; ++j) {
        int yy = y0 + j - R;                               // uniform per block
        float4 a0 = make_float4(0.f, 0.f, 0.f, 0.f), a1 = a0, a2 = a0;
        if ((unsigned)yy < 128u) {
            int base = zs + yy * 128 + x0;
            a0 = *(const float4*)(A + base);
            a1 = *(const float4*)(A + NV + base);
            a2 = *(const float4*)(A + 2 * NV + base);
        }
#pragma unroll
        for (int t = 0; t < 4; ++t) {
            int i = j - t + 3;
            float w0 = kp[0][i], w1 = kp[1][i], w2 = kp[2][i];
            fma4(acc[0][t], w0, a0);
            fma4(acc[1][t], w1, a0);
            fma4(acc[2][t], w2, a0);
            fma4(acc[3][t], w0, a1);
            fma4(acc[4][t], w1, a1);
            fma4(acc[5][t], w0, a2);
        }
    }
#pragma unroll
    for (int t = 0; t < 4; ++t)
#pragma unroll
        for (int c = 0; c < 6; ++c)
            *(float4*)(&Bs[tz * 4 + t][c][x0]) = acc[c][t];

    __syncthreads();

    // ---- phase 2: x-conv + epilogue; thread -> row rr, quads q0+8k ----
    const int rr = threadIdx.x >> 3;                       // 0..15
    const int q0 = threadIdx.x & 7;
    const int z2 = zbase + (rr >> 2);
    const int y2 = y0 + (rr & 3);
    const int vrow = (z2 * 128 + y2) * 128;

#pragma unroll 1
    for (int k = 0; k < 4; ++k) {
        const int xb = 4 * (q0 + 8 * k);
        float g000[4] = {0,0,0,0}, g001[4] = {0,0,0,0}, g002[4] = {0,0,0,0},
              g010[4] = {0,0,0,0}, g011[4] = {0,0,0,0}, g020[4] = {0,0,0,0},
              g100[4] = {0,0,0,0}, g101[4] = {0,0,0,0}, g110[4] = {0,0,0,0},
              g200[4] = {0,0,0,0};

        convx_lds<3>(&Bs[rr][0][0], xb, kw, g000, g001, g002);
        convx_lds<2>(&Bs[rr][1][0], xb, kw, g010, g011, g011);
        convx_lds<1>(&Bs[rr][2][0], xb, kw, g020, g020, g020);
        convx_lds<2>(&Bs[rr][3][0], xb, kw, g100, g101, g101);
        convx_lds<1>(&Bs[rr][4][0], xb, kw, g110, g110, g110);
        convx_lds<1>(&Bs[rr][5][0], xb, kw, g200, g200, g200);

#pragma unroll
        for (int t = 0; t < 4; ++t) {
            int v = vrow + xb + t;
            if (seg[v] == (ST)label) {
                float mass = g000[t];
                float denom = (mass > 0.f) ? mass : 1.f;
                float inv = 1.f / denom;
                float p = g100[t] * inv, q = g010[t] * inv, s = g001[t] * inv;
                const float cs = 1.0f / 25.0f;             // 1/sigma^2
                float o[10];
                o[0] = 0.5f - 0.1f * p;                    // 1/(2 sigma) = 0.1
                o[1] = 0.5f - 0.1f * q;
                o[2] = 0.5f - 0.1f * s;
                o[3] = (g200[t] * inv - p * p) * cs;
                o[4] = (g020[t] * inv - q * q) * cs;
                o[5] = (g002[t] * inv - s * s) * cs;
                o[6] = (g110[t] * inv - p * q) * cs;
                o[7] = (g011[t] * inv - q * s) * cs;
                o[8] = (g101[t] * inv - p * s) * cs;
                o[9] = mass;
#pragma unroll
                for (int c = 0; c < 10; ++c) {
                    float val = fminf(fmaxf(o[c], 0.f), 1.f);
                    out[(size_t)c * NV + v] = val;
                }
            }
        }
    }
}

__global__ __launch_bounds__(256) void seg_to_u8(const int* __restrict__ seg,
                                                 unsigned char* __restrict__ seg8) {
    const int t = blockIdx.x * 256 + threadIdx.x;          // 2048 blocks
    const int4 s = ((const int4*)seg)[t];
    ((uchar4*)seg8)[t] = make_uchar4((unsigned char)s.x, (unsigned char)s.y,
                                     (unsigned char)s.z, (unsigned char)s.w);
}

extern "C" void kernel_launch(void* const* d_in, const int* in_sizes, int n_in,
                              void* d_out, int out_size, void* d_ws, size_t ws_size,
                              hipStream_t stream) {
    const int* seg = (const int*)d_in[0];
    // d_in[1] (coords) unused: math is translation-invariant.
    float* out = (float*)d_out;
    float* A = (float*)d_ws;                               // 3 volumes (24 MB)
    unsigned char* seg8 = (unsigned char*)(A + (size_t)3 * NV);
    const bool use8 = ws_size >= (size_t)3 * NV * sizeof(float) + NV;

    Kw kw;
    double gg[KL], S = 0.0;
    for (int j = 0; j < KL; ++j) { double d = j - R; gg[j] = exp(-0.5 * d * d / 25.0); S += gg[j]; }
    for (int j = 0; j < KL; ++j) {
        double gn = gg[j] / S, d = j - R;
        kw.k0[j] = (float)gn;
        kw.k1[j] = (float)(-d * gn);   // conv kernel k1 evaluated at (Z - t) = -d
        kw.k2[j] = (float)(d * d * gn);
    }

    hipMemsetAsync(d_out, 0, (size_t)out_size * sizeof(float), stream);

    if (use8) seg_to_u8<<<dim3(2048), dim3(256), 0, stream>>>(seg, seg8);
    for (int label = 1; label <= 8; ++label) {
        if (use8) {
            pass_z_t<unsigned char><<<dim3(512), dim3(256), 0, stream>>>(seg8, A, label, kw);
            pass_yx<unsigned char><<<dim3(1024), dim3(128), 0, stream>>>(A, seg8, out, label, kw);
        } else {
            pass_z_t<int><<<dim3(512), dim3(256), 0, stream>>>(seg, A, label, kw);
            pass_yx<int><<<dim3(1024), dim3(128), 0, stream>>>(A, seg, out, label, kw);
        }
    }
}